// Round 15
// baseline (38.801 us; speedup 1.0000x reference)
//
#include <hip/hip_runtime.h>
#include <hip/hip_bf16.h>

// AggregationLoss. preds [32,6,256,256] f32, targets [32,2,256,256] i32.
// sim = preds[:,2:6]; text = targets[:,0]; kernel = targets[:,1]; MAX_T=16.
// Per sample: G[t] = mean of sim over kernel==t; per-pixel
// loss = log1p(max(||sim_p - G[text_p]|| - 0.5, 0)^2); per-instance mean over
// text==t for valid t (t>=1, k_cnt>0, t_cnt>0); output = mean over valid.
//
// R15 = R14 (24.9us) minus K3: every K2 block computes scale locally and
// atomicAdds blocksum*scale into out[s] (2048 atomics ~ 0.6us, R1 calib);
// K1 zeroes out[] (kernel boundary orders the store before K2's atomics).
// K2: NB2 64 (1 float4/thread, 8 blocks/CU) + 180-thread parallel preamble.
// Kept: K1 private-LDS scatter (R14), bit-sliced counts (R12), linearity
// (R11), DPP reduce (R7), no fences (R10), no coop (R9), no min-waves (R6).

#define P_PIX 65536
#define NS 32
#define NB1 32             // K1 blocks/sample; 1024 blocks x 128 thr, 16 px/thr
#define NB2 64             // K2 blocks/sample; 2048 blocks x 256 thr, 4 px/thr
#define SP_F 96            // stats partial: kcnt[0..14] ksum[15..74] tcnt[75..89]
#define WS_STATS_OFF 0

typedef float v2f __attribute__((ext_vector_type(2)));

// ---- DPP wave(64) sum: result lands in lane 63 (R7 proven) ----
template <int CTRL, int RM>
__device__ __forceinline__ float dpp_mov_f(float v) {
    return __int_as_float(
        __builtin_amdgcn_update_dpp(0, __float_as_int(v), CTRL, RM, 0xf, true));
}
template <int CTRL, int RM>
__device__ __forceinline__ int dpp_mov_i(int v) {
    return __builtin_amdgcn_update_dpp(0, v, CTRL, RM, 0xf, true);
}
__device__ __forceinline__ float wave_sum_f(float v) {
    v += dpp_mov_f<0x111, 0xf>(v);
    v += dpp_mov_f<0x112, 0xf>(v);
    v += dpp_mov_f<0x114, 0xf>(v);
    v += dpp_mov_f<0x118, 0xf>(v);
    v += dpp_mov_f<0x142, 0xa>(v);
    v += dpp_mov_f<0x143, 0xc>(v);
    return v;
}
__device__ __forceinline__ unsigned int wave_sum_u(unsigned int v) {
    v += (unsigned int)dpp_mov_i<0x111, 0xf>((int)v);
    v += (unsigned int)dpp_mov_i<0x112, 0xf>((int)v);
    v += (unsigned int)dpp_mov_i<0x114, 0xf>((int)v);
    v += (unsigned int)dpp_mov_i<0x118, 0xf>((int)v);
    v += (unsigned int)dpp_mov_i<0x142, 0xa>((int)v);
    v += (unsigned int)dpp_mov_i<0x143, 0xc>((int)v);
    return v;
}

// ---------------- K1: segment stats (private-LDS scatter, R14) -------------

#define ROWF 34            // floats per row (16 bins x 2 ch + 2 pad)

__global__ __launch_bounds__(128) void agg_stats_kernel(
        const float* __restrict__ preds,
        const int* __restrict__ targets,
        float* __restrict__ ws,
        float* __restrict__ out) {
    const int s = blockIdx.y;
    const int b = blockIdx.x;
    const int tid = threadIdx.x;      // 0..127
    const int lane = tid & 63;
    const int w = tid >> 6;           // wave 0/1

    // zero the output accumulator (K2 atomicAdds into it; kernel boundary
    // guarantees ordering/visibility)
    if (b == 0 && tid == 0) out[s] = 0.0f;

    // acc[region][row][bin*2 + (ch&1)]: region 0 = ch{0,1}, 1 = ch{2,3}
    __shared__ __align__(16) float acc[2][128][ROWF];     // 34816 B
    {
        float4* a4 = (float4*)acc;    // 2176 float4
        #pragma unroll
        for (int i = 0; i < 17; ++i)
            a4[i * 128 + tid] = make_float4(0.f, 0.f, 0.f, 0.f);
    }
    __syncthreads();

    // bit-sliced counters, two 8-px halves (4-bit fields cap 15)
    unsigned long long kp[2] = {0ull, 0ull}, tp[2] = {0ull, 0ull};

    const float* sim  = preds + (size_t)s * 6 * P_PIX + 2 * (size_t)P_PIX;
    const int*   text = targets + (size_t)s * 2 * P_PIX;
    const int*   kern = text + P_PIX;

    float* row01 = &acc[0][tid][0];
    float* row23 = &acc[1][tid][0];

    #pragma unroll
    for (int it = 0; it < 4; ++it) {
        const int p4 = b * 512 + it * 128 + tid;    // float4 index
        const int4   tb4 = ((const int4*)text)[p4];
        const int4   kb4 = ((const int4*)kern)[p4];
        const float4 v0 = ((const float4*)(sim))[p4];
        const float4 v1 = ((const float4*)(sim + P_PIX))[p4];
        const float4 v2 = ((const float4*)(sim + 2 * P_PIX))[p4];
        const float4 v3 = ((const float4*)(sim + 3 * P_PIX))[p4];
        const int tbv[4] = {tb4.x, tb4.y, tb4.z, tb4.w};
        const int kbv[4] = {kb4.x, kb4.y, kb4.z, kb4.w};
        const v2f a01[4] = {{v0.x, v1.x}, {v0.y, v1.y}, {v0.z, v1.z}, {v0.w, v1.w}};
        const v2f a23[4] = {{v2.x, v3.x}, {v2.y, v3.y}, {v2.z, v3.z}, {v2.w, v3.w}};
        const int h = it >> 1;
        #pragma unroll
        for (int j = 0; j < 4; ++j) {
            const int kb = kbv[j], tb = tbv[j];
            kp[h] += 1ull << (4 * kb);
            tp[h] += 1ull << (4 * tb);
            v2f* p01 = (v2f*)&row01[kb * 2];
            v2f* p23 = (v2f*)&row23[kb * 2];
            *p01 = *p01 + a01[j];     // plain DS RMW: same-wave pipe-ordered
            *p23 = *p23 + a23[j];
        }
    }

    // counts: 4-bit -> 16-bit expansion (merge halves at 8-bit stage)
    const unsigned long long M4 = 0x0F0F0F0F0F0F0F0Full;
    const unsigned long long M8 = 0x00FF00FF00FF00FFull;
    unsigned int kc[8], tc[8];
    {
        unsigned long long e = (kp[0] & M4) + (kp[1] & M4);
        unsigned long long o = ((kp[0] >> 4) & M4) + ((kp[1] >> 4) & M4);
        unsigned long long e0 = e & M8, e1 = (e >> 8) & M8;
        unsigned long long o0 = o & M8, o1 = (o >> 8) & M8;
        kc[0] = (unsigned int)e0; kc[1] = (unsigned int)(e0 >> 32);
        kc[2] = (unsigned int)e1; kc[3] = (unsigned int)(e1 >> 32);
        kc[4] = (unsigned int)o0; kc[5] = (unsigned int)(o0 >> 32);
        kc[6] = (unsigned int)o1; kc[7] = (unsigned int)(o1 >> 32);
    }
    {
        unsigned long long e = (tp[0] & M4) + (tp[1] & M4);
        unsigned long long o = ((tp[0] >> 4) & M4) + ((tp[1] >> 4) & M4);
        unsigned long long e0 = e & M8, e1 = (e >> 8) & M8;
        unsigned long long o0 = o & M8, o1 = (o >> 8) & M8;
        tc[0] = (unsigned int)e0; tc[1] = (unsigned int)(e0 >> 32);
        tc[2] = (unsigned int)e1; tc[3] = (unsigned int)(e1 >> 32);
        tc[4] = (unsigned int)o0; tc[5] = (unsigned int)(o0 >> 32);
        tc[6] = (unsigned int)o1; tc[7] = (unsigned int)(o1 >> 32);
    }
    #pragma unroll
    for (int k = 0; k < 8; ++k) { kc[k] = wave_sum_u(kc[k]); tc[k] = wave_sum_u(tc[k]); }

    __shared__ unsigned int wk[2][8], wt[2][8];
    __shared__ float colred[64][2];
    if (lane == 63) {
        #pragma unroll
        for (int k = 0; k < 8; ++k) { wk[w][k] = kc[k]; wt[w][k] = tc[k]; }
    }
    __syncthreads();

    // ksum column sums: 64 cols x 128 rows
    {
        const int col = tid & 63;
        const int q = tid >> 6;
        const int bin = col >> 2, ch = col & 3;
        const int region = ch >> 1, sub = ch & 1;
        float sum = 0.0f;
        #pragma unroll 16
        for (int r = 0; r < 64; ++r)
            sum += acc[region][q * 64 + r][bin * 2 + sub];
        colred[col][q] = sum;
    }
    __syncthreads();

    float* part = ws + WS_STATS_OFF + (size_t)(s * NB1 + b) * SP_F;
    if (tid < 64) {
        const int bin = tid >> 2, ch = tid & 3;
        if (bin >= 1)
            part[15 + (bin - 1) * 4 + ch] = colred[tid][0] + colred[tid][1];
    } else if (tid >= 64 && tid < 94) {
        const int k = tid - 64;
        const int bin = (k < 15) ? (k + 1) : (k - 14);
        const unsigned int (*src)[8] = (k < 15) ? wk : wt;
        const int u = (bin & 1) * 2 + ((bin >> 1) & 1);
        const int f = bin >> 2;
        const int idx = u * 2 + (f >> 1);
        const int sh = (f & 1) * 16;
        const unsigned int sum = src[0][idx] + src[1][idx];
        part[(k < 15) ? k : (75 + k - 15)] = (float)((sum >> sh) & 0xFFFFu);
    }
}

// ---------------- K2: weighted loss + per-block atomic finalize ------------

__global__ __launch_bounds__(256) void agg_loss_kernel(
        const float* __restrict__ preds,
        const int* __restrict__ targets,
        const float* __restrict__ ws,
        float* __restrict__ out) {
    const int s = blockIdx.y;
    const int b = blockIdx.x;
    const int tid = threadIdx.x;
    const int lane = tid & 63;
    const int w = tid >> 6;

    __shared__ float tmp2[2][90];
    __shared__ float tmp[90];
    __shared__ __align__(16) float4 G4[16];   // G4[0] = 0 (background dummy)
    __shared__ float w16[16];                 // w[t] = valid ? 1/t_cnt : 0
    __shared__ float ip[4];
    __shared__ float sscale;

    // parallel preamble: 180 threads, 2 chunks of 16 partials each
    if (tid < 180) {
        const int c = (tid >= 90) ? 1 : 0;
        const int v = tid - c * 90;
        const float* base = ws + WS_STATS_OFF + (size_t)s * NB1 * SP_F + v;
        float a = 0.0f;
        #pragma unroll
        for (int pb = c * 16; pb < c * 16 + 16; ++pb) a += base[pb * SP_F];
        tmp2[c][v] = a;
    }
    __syncthreads();
    if (tid < 90) tmp[tid] = tmp2[0][tid] + tmp2[1][tid];
    __syncthreads();
    if (tid < 60) ((float*)G4)[4 + tid] = tmp[15 + tid] / fmaxf(tmp[tid >> 2], 1.0f);
    if (tid >= 64 && tid < 68) ((float*)G4)[tid - 64] = 0.0f;
    if (tid < 16) {
        if (tid == 15) {
            w16[0] = 0.0f;
        } else {
            const float kcv = tmp[tid];
            const float tcv = tmp[75 + tid];
            w16[tid + 1] = (kcv > 0.0f && tcv > 0.0f) ? 1.0f / tcv : 0.0f;
        }
    }
    if (tid == 0) {
        float nv = 0.0f;
        #pragma unroll
        for (int t = 0; t < 15; ++t)
            nv += (tmp[t] > 0.0f && tmp[75 + t] > 0.0f) ? 1.0f : 0.0f;
        sscale = (nv > 0.0f) ? 1.0f / nv : 0.0f;
    }
    __syncthreads();

    const float* sim  = preds + (size_t)s * 6 * P_PIX + 2 * (size_t)P_PIX;
    const int*   text = targets + (size_t)s * 2 * P_PIX;

    float racc = 0.0f;
    {
        const int p4 = b * 256 + tid;     // 64 blocks x 256 thr = 16384 float4
        const int4   tb4 = ((const int4*)text)[p4];
        const float4 v0 = ((const float4*)(sim))[p4];
        const float4 v1 = ((const float4*)(sim + P_PIX))[p4];
        const float4 v2 = ((const float4*)(sim + 2 * P_PIX))[p4];
        const float4 v3 = ((const float4*)(sim + 3 * P_PIX))[p4];
        const int tbv[4] = {tb4.x, tb4.y, tb4.z, tb4.w};
        const float a[4][4] = {{v0.x, v1.x, v2.x, v3.x}, {v0.y, v1.y, v2.y, v3.y},
                               {v0.z, v1.z, v2.z, v3.z}, {v0.w, v1.w, v2.w, v3.w}};
        #pragma unroll
        for (int j = 0; j < 4; ++j) {
            const int tb = tbv[j];
            const float4 g = G4[tb];
            const float wv = w16[tb];
            const float d0 = a[j][0] - g.x;
            const float d1 = a[j][1] - g.y;
            const float d2 = a[j][2] - g.z;
            const float d3 = a[j][3] - g.w;
            const float dd = sqrtf(d0 * d0 + d1 * d1 + d2 * d2 + d3 * d3) - 0.5f;
            const float r = fmaxf(dd, 0.0f);
            const float lp = __logf(fmaf(r, r, 1.0f));   // ln(1+r^2)
            racc = fmaf(lp, wv, racc);
        }
    }

    racc = wave_sum_f(racc);
    if (lane == 63) ip[w] = racc;
    __syncthreads();
    if (tid == 0) {
        const float blocksum = (ip[0] + ip[1]) + (ip[2] + ip[3]);
        atomicAdd(&out[s], blocksum * sscale);
    }
}

extern "C" void kernel_launch(void* const* d_in, const int* in_sizes, int n_in,
                              void* d_out, int out_size, void* d_ws, size_t ws_size,
                              hipStream_t stream) {
    const float* preds = (const float*)d_in[0];
    const int* targets = (const int*)d_in[1];
    float* out = (float*)d_out;
    float* ws = (float*)d_ws;

    agg_stats_kernel<<<dim3(NB1, NS), 128, 0, stream>>>(preds, targets, ws, out);
    agg_loss_kernel<<<dim3(NB2, NS), 256, 0, stream>>>(preds, targets, ws, out);
}

// Round 16
// 24.513 us; speedup vs baseline: 1.5828x; 1.5828x over previous
//
#include <hip/hip_runtime.h>
#include <hip/hip_bf16.h>

// AggregationLoss. preds [32,6,256,256] f32, targets [32,2,256,256] i32.
// sim = preds[:,2:6]; text = targets[:,0]; kernel = targets[:,1]; MAX_T=16.
// Per sample: G[t] = mean of sim over kernel==t; per-pixel
// loss = log1p(max(||sim_p - G[text_p]|| - 0.5, 0)^2); per-instance mean over
// text==t for valid t (t>=1, k_cnt>0, t_cnt>0); output = mean over valid.
//
// R16 = R14 (24.9us best) + ONE tweak: K2 preamble parallelized over 180
// threads (2 chunks of 16 partials), halving the serial add chain.
// R15 lesson (38.8us): NEVER atomicAdd a dense output array - 2048 atomics
// into 2 cache lines serialize at L2 (~150cyc each). Atomics/line is the
// metric, not atomic count. K3 (kernel-boundary reduction) restored.
// Kept: K1 private-LDS scatter (R14), bit-sliced counts (R12), linearity
// (R11), DPP reduce (R7), no fences (R10), no coop (R9), no min-waves (R6).

#define P_PIX 65536
#define NS 32
#define NB1 32             // K1 blocks/sample; 1024 blocks x 128 thr, 16 px/thr
#define NB2 32             // K2 blocks/sample; 1024 blocks x 256 thr, 8 px/thr
#define SP_F 96            // stats partial: kcnt[0..14] ksum[15..74] tcnt[75..89]
#define WS_STATS_OFF 0
#define WS_LP_OFF (NS * NB1 * SP_F)         // loss partials: [NS][NB2] floats
#define WS_SC_OFF (WS_LP_OFF + NS * NB2)    // scale (1/n_valid): [NS] floats

typedef float v2f __attribute__((ext_vector_type(2)));

// ---- DPP wave(64) sum: result lands in lane 63 (R7 proven) ----
template <int CTRL, int RM>
__device__ __forceinline__ float dpp_mov_f(float v) {
    return __int_as_float(
        __builtin_amdgcn_update_dpp(0, __float_as_int(v), CTRL, RM, 0xf, true));
}
template <int CTRL, int RM>
__device__ __forceinline__ int dpp_mov_i(int v) {
    return __builtin_amdgcn_update_dpp(0, v, CTRL, RM, 0xf, true);
}
__device__ __forceinline__ float wave_sum_f(float v) {
    v += dpp_mov_f<0x111, 0xf>(v);
    v += dpp_mov_f<0x112, 0xf>(v);
    v += dpp_mov_f<0x114, 0xf>(v);
    v += dpp_mov_f<0x118, 0xf>(v);
    v += dpp_mov_f<0x142, 0xa>(v);
    v += dpp_mov_f<0x143, 0xc>(v);
    return v;
}
__device__ __forceinline__ unsigned int wave_sum_u(unsigned int v) {
    v += (unsigned int)dpp_mov_i<0x111, 0xf>((int)v);
    v += (unsigned int)dpp_mov_i<0x112, 0xf>((int)v);
    v += (unsigned int)dpp_mov_i<0x114, 0xf>((int)v);
    v += (unsigned int)dpp_mov_i<0x118, 0xf>((int)v);
    v += (unsigned int)dpp_mov_i<0x142, 0xa>((int)v);
    v += (unsigned int)dpp_mov_i<0x143, 0xc>((int)v);
    return v;
}

// ---------------- K1: segment stats (private-LDS scatter, R14) -------------

#define ROWF 34            // floats per row (16 bins x 2 ch + 2 pad)

__global__ __launch_bounds__(128) void agg_stats_kernel(
        const float* __restrict__ preds,
        const int* __restrict__ targets,
        float* __restrict__ ws) {
    const int s = blockIdx.y;
    const int b = blockIdx.x;
    const int tid = threadIdx.x;      // 0..127
    const int lane = tid & 63;
    const int w = tid >> 6;           // wave 0/1

    // acc[region][row][bin*2 + (ch&1)]: region 0 = ch{0,1}, 1 = ch{2,3}
    __shared__ __align__(16) float acc[2][128][ROWF];     // 34816 B
    {
        float4* a4 = (float4*)acc;    // 2176 float4
        #pragma unroll
        for (int i = 0; i < 17; ++i)
            a4[i * 128 + tid] = make_float4(0.f, 0.f, 0.f, 0.f);
    }
    __syncthreads();

    // bit-sliced counters, two 8-px halves (4-bit fields cap 15)
    unsigned long long kp[2] = {0ull, 0ull}, tp[2] = {0ull, 0ull};

    const float* sim  = preds + (size_t)s * 6 * P_PIX + 2 * (size_t)P_PIX;
    const int*   text = targets + (size_t)s * 2 * P_PIX;
    const int*   kern = text + P_PIX;

    float* row01 = &acc[0][tid][0];
    float* row23 = &acc[1][tid][0];

    #pragma unroll
    for (int it = 0; it < 4; ++it) {
        const int p4 = b * 512 + it * 128 + tid;    // float4 index
        const int4   tb4 = ((const int4*)text)[p4];
        const int4   kb4 = ((const int4*)kern)[p4];
        const float4 v0 = ((const float4*)(sim))[p4];
        const float4 v1 = ((const float4*)(sim + P_PIX))[p4];
        const float4 v2 = ((const float4*)(sim + 2 * P_PIX))[p4];
        const float4 v3 = ((const float4*)(sim + 3 * P_PIX))[p4];
        const int tbv[4] = {tb4.x, tb4.y, tb4.z, tb4.w};
        const int kbv[4] = {kb4.x, kb4.y, kb4.z, kb4.w};
        const v2f a01[4] = {{v0.x, v1.x}, {v0.y, v1.y}, {v0.z, v1.z}, {v0.w, v1.w}};
        const v2f a23[4] = {{v2.x, v3.x}, {v2.y, v3.y}, {v2.z, v3.z}, {v2.w, v3.w}};
        const int h = it >> 1;
        #pragma unroll
        for (int j = 0; j < 4; ++j) {
            const int kb = kbv[j], tb = tbv[j];
            kp[h] += 1ull << (4 * kb);
            tp[h] += 1ull << (4 * tb);
            v2f* p01 = (v2f*)&row01[kb * 2];
            v2f* p23 = (v2f*)&row23[kb * 2];
            *p01 = *p01 + a01[j];     // plain DS RMW: same-wave pipe-ordered
            *p23 = *p23 + a23[j];
        }
    }

    // counts: 4-bit -> 16-bit expansion (merge halves at 8-bit stage)
    const unsigned long long M4 = 0x0F0F0F0F0F0F0F0Full;
    const unsigned long long M8 = 0x00FF00FF00FF00FFull;
    unsigned int kc[8], tc[8];
    {
        unsigned long long e = (kp[0] & M4) + (kp[1] & M4);
        unsigned long long o = ((kp[0] >> 4) & M4) + ((kp[1] >> 4) & M4);
        unsigned long long e0 = e & M8, e1 = (e >> 8) & M8;
        unsigned long long o0 = o & M8, o1 = (o >> 8) & M8;
        kc[0] = (unsigned int)e0; kc[1] = (unsigned int)(e0 >> 32);
        kc[2] = (unsigned int)e1; kc[3] = (unsigned int)(e1 >> 32);
        kc[4] = (unsigned int)o0; kc[5] = (unsigned int)(o0 >> 32);
        kc[6] = (unsigned int)o1; kc[7] = (unsigned int)(o1 >> 32);
    }
    {
        unsigned long long e = (tp[0] & M4) + (tp[1] & M4);
        unsigned long long o = ((tp[0] >> 4) & M4) + ((tp[1] >> 4) & M4);
        unsigned long long e0 = e & M8, e1 = (e >> 8) & M8;
        unsigned long long o0 = o & M8, o1 = (o >> 8) & M8;
        tc[0] = (unsigned int)e0; tc[1] = (unsigned int)(e0 >> 32);
        tc[2] = (unsigned int)e1; tc[3] = (unsigned int)(e1 >> 32);
        tc[4] = (unsigned int)o0; tc[5] = (unsigned int)(o0 >> 32);
        tc[6] = (unsigned int)o1; tc[7] = (unsigned int)(o1 >> 32);
    }
    #pragma unroll
    for (int k = 0; k < 8; ++k) { kc[k] = wave_sum_u(kc[k]); tc[k] = wave_sum_u(tc[k]); }

    __shared__ unsigned int wk[2][8], wt[2][8];
    __shared__ float colred[64][2];
    if (lane == 63) {
        #pragma unroll
        for (int k = 0; k < 8; ++k) { wk[w][k] = kc[k]; wt[w][k] = tc[k]; }
    }
    __syncthreads();

    // ksum column sums: 64 cols x 128 rows
    {
        const int col = tid & 63;
        const int q = tid >> 6;
        const int bin = col >> 2, ch = col & 3;
        const int region = ch >> 1, sub = ch & 1;
        float sum = 0.0f;
        #pragma unroll 16
        for (int r = 0; r < 64; ++r)
            sum += acc[region][q * 64 + r][bin * 2 + sub];
        colred[col][q] = sum;
    }
    __syncthreads();

    float* part = ws + WS_STATS_OFF + (size_t)(s * NB1 + b) * SP_F;
    if (tid < 64) {
        const int bin = tid >> 2, ch = tid & 3;
        if (bin >= 1)
            part[15 + (bin - 1) * 4 + ch] = colred[tid][0] + colred[tid][1];
    } else if (tid >= 64 && tid < 94) {
        const int k = tid - 64;
        const int bin = (k < 15) ? (k + 1) : (k - 14);
        const unsigned int (*src)[8] = (k < 15) ? wk : wt;
        const int u = (bin & 1) * 2 + ((bin >> 1) & 1);
        const int f = bin >> 2;
        const int idx = u * 2 + (f >> 1);
        const int sh = (f & 1) * 16;
        const unsigned int sum = src[0][idx] + src[1][idx];
        part[(k < 15) ? k : (75 + k - 15)] = (float)((sum >> sh) & 0xFFFFu);
    }
}

// ---------------- K2: weighted loss (R11 linearity; parallel preamble) -----

__global__ __launch_bounds__(256) void agg_loss_kernel(
        const float* __restrict__ preds,
        const int* __restrict__ targets,
        float* __restrict__ ws) {
    const int s = blockIdx.y;
    const int b = blockIdx.x;
    const int tid = threadIdx.x;
    const int lane = tid & 63;
    const int w = tid >> 6;

    __shared__ float tmp2[2][90];
    __shared__ float tmp[90];
    __shared__ __align__(16) float4 G4[16];   // G4[0] = 0 (background dummy)
    __shared__ float w16[16];                 // w[t] = valid ? 1/t_cnt : 0
    __shared__ float ip[4];

    // parallel preamble: 180 threads, 2 chunks of 16 partials each
    if (tid < 180) {
        const int c = (tid >= 90) ? 1 : 0;
        const int v = tid - c * 90;
        const float* base = ws + WS_STATS_OFF + (size_t)s * NB1 * SP_F + v;
        float a = 0.0f;
        #pragma unroll
        for (int pb = c * 16; pb < c * 16 + 16; ++pb) a += base[pb * SP_F];
        tmp2[c][v] = a;
    }
    __syncthreads();
    if (tid < 90) tmp[tid] = tmp2[0][tid] + tmp2[1][tid];
    __syncthreads();
    if (tid < 60) ((float*)G4)[4 + tid] = tmp[15 + tid] / fmaxf(tmp[tid >> 2], 1.0f);
    if (tid >= 64 && tid < 68) ((float*)G4)[tid - 64] = 0.0f;
    if (tid < 16) {
        if (tid == 15) {
            w16[0] = 0.0f;
        } else {
            const float kcv = tmp[tid];
            const float tcv = tmp[75 + tid];
            w16[tid + 1] = (kcv > 0.0f && tcv > 0.0f) ? 1.0f / tcv : 0.0f;
        }
    }
    if (w == 0) {
        const bool vld = (tid < 15) && (tmp[tid] > 0.0f) && (tmp[75 + tid] > 0.0f);
        const unsigned long long m = __ballot(vld);
        if (b == 0 && tid == 0) {
            const float nv = (float)__popcll(m);
            ws[WS_SC_OFF + s] = (nv > 0.0f) ? 1.0f / nv : 0.0f;
        }
    }
    __syncthreads();

    const float* sim  = preds + (size_t)s * 6 * P_PIX + 2 * (size_t)P_PIX;
    const int*   text = targets + (size_t)s * 2 * P_PIX;

    float racc = 0.0f;
    #pragma unroll
    for (int it = 0; it < 2; ++it) {
        const int p4 = b * 512 + it * 256 + tid;
        const int4   tb4 = ((const int4*)text)[p4];
        const float4 v0 = ((const float4*)(sim))[p4];
        const float4 v1 = ((const float4*)(sim + P_PIX))[p4];
        const float4 v2 = ((const float4*)(sim + 2 * P_PIX))[p4];
        const float4 v3 = ((const float4*)(sim + 3 * P_PIX))[p4];
        const int tbv[4] = {tb4.x, tb4.y, tb4.z, tb4.w};
        const float a[4][4] = {{v0.x, v1.x, v2.x, v3.x}, {v0.y, v1.y, v2.y, v3.y},
                               {v0.z, v1.z, v2.z, v3.z}, {v0.w, v1.w, v2.w, v3.w}};
        #pragma unroll
        for (int j = 0; j < 4; ++j) {
            const int tb = tbv[j];
            const float4 g = G4[tb];
            const float wv = w16[tb];
            const float d0 = a[j][0] - g.x;
            const float d1 = a[j][1] - g.y;
            const float d2 = a[j][2] - g.z;
            const float d3 = a[j][3] - g.w;
            const float dd = sqrtf(d0 * d0 + d1 * d1 + d2 * d2 + d3 * d3) - 0.5f;
            const float r = fmaxf(dd, 0.0f);
            const float lp = __logf(fmaf(r, r, 1.0f));   // ln(1+r^2)
            racc = fmaf(lp, wv, racc);
        }
    }

    racc = wave_sum_f(racc);
    if (lane == 63) ip[w] = racc;
    __syncthreads();
    if (tid == 0)
        ws[WS_LP_OFF + (size_t)s * NB2 + b] = (ip[0] + ip[1]) + (ip[2] + ip[3]);
}

// ---------------- K3: per-sample sum of 32 partials x scale ----------------

__global__ __launch_bounds__(64) void agg_final_kernel(
        const float* __restrict__ ws, float* __restrict__ out) {
    const int s = blockIdx.x;
    const int tid = threadIdx.x;
    float v = (tid < NB2) ? ws[WS_LP_OFF + (size_t)s * NB2 + tid] : 0.0f;
    #pragma unroll
    for (int off = 32; off >= 1; off >>= 1) v += __shfl_down(v, off);
    if (tid == 0) out[s] = v * ws[WS_SC_OFF + s];
}

extern "C" void kernel_launch(void* const* d_in, const int* in_sizes, int n_in,
                              void* d_out, int out_size, void* d_ws, size_t ws_size,
                              hipStream_t stream) {
    const float* preds = (const float*)d_in[0];
    const int* targets = (const int*)d_in[1];
    float* out = (float*)d_out;
    float* ws = (float*)d_ws;

    agg_stats_kernel<<<dim3(NB1, NS), 128, 0, stream>>>(preds, targets, ws);
    agg_loss_kernel<<<dim3(NB2, NS), 256, 0, stream>>>(preds, targets, ws);
    agg_final_kernel<<<NS, 64, 0, stream>>>(ws, out);
}